// Round 19
// baseline (190.580 us; speedup 1.0000x reference)
//
#include <hip/hip_runtime.h>

// ---------------------------------------------------------------------------
// SelfAttention fused pipeline for MI355X (gfx950)
// B=4 S=1024 DIM=2048 H=16 KV=4 HD=128 ROPE_DIM=64
//
// Stages (all on `stream`), 5 launches:
//  1) prep: casts fp32->bf16 (x | Wq|Wk|Wv | Wproj) + rope cos/sin table
//  2a) gemm_bt<MODE=1>: qk part of qkv (640 blocks) + RMSNorm/RoPE/log2
//      prescale epilogue  (separate kernel -> lean regalloc, R12-class occ)
//  2b) gemm_bt<MODE=2>: v part of qkv (128 blocks) + pad-137 LDS transpose
//      -> vt (pre-swizzled for attn staging)
//  3) attn_fwd: causal flash attention + v-proj correction -> y bf16
//     (KVBLK=128 sequential-pair, ones-MFMA denom, defer-max)
//  4) gemm_bt<MODE=0>: out = y @ Wproj^T (fp32 out)
// ---------------------------------------------------------------------------

typedef __attribute__((ext_vector_type(8))) __bf16 bf16x8;
typedef __attribute__((ext_vector_type(4))) __bf16 bf16x4;
typedef __attribute__((ext_vector_type(4))) float f32x4;

static_assert(sizeof(__bf16) == 2, "bf16 size");

#define MFMA16x16x32(a, b, c) __builtin_amdgcn_mfma_f32_16x16x32_bf16((a), (b), (c), 0, 0, 0)

#if __has_builtin(__builtin_amdgcn_exp2f)
#define EXP2(x) __builtin_amdgcn_exp2f(x)
#else
#define EXP2(x) exp2f(x)
#endif

__device__ __forceinline__ void gload_lds16(const void* g, void* l) {
  __builtin_amdgcn_global_load_lds((const __attribute__((address_space(1))) void*)g,
                                   (__attribute__((address_space(3))) void*)l, 16, 0, 0);
}

// ---------------- 1) prep: all casts + rope table, one kernel ----------------
__global__ __launch_bounds__(256) void prep(const float* __restrict__ x,
                                            const float* __restrict__ wq,
                                            const float* __restrict__ wk,
                                            const float* __restrict__ wv,
                                            const float* __restrict__ wp,
                                            __bf16* __restrict__ xb,
                                            __bf16* __restrict__ wb,
                                            __bf16* __restrict__ wpb,
                                            float2* __restrict__ tab) {
  constexpr int NX = 2097152;   // 4096*2048/4
  constexpr int NW1 = 1048576;  // 2048*2048/4
  constexpr int NW2 = 262144;   // 512*2048/4
  constexpr int NP = 1048576;   // 2048*2048/4
  constexpr int NT = 32768;     // 1024*32 rope table entries
  constexpr int TOT = NX + NW1 + 2 * NW2 + NP + NT;
  auto cast4 = [](const float* s, __bf16* d, int i) {
    f32x4 v = ((const f32x4*)s)[i];
    bf16x4 o;
    o[0] = (__bf16)v[0];
    o[1] = (__bf16)v[1];
    o[2] = (__bf16)v[2];
    o[3] = (__bf16)v[3];
    ((bf16x4*)d)[i] = o;
  };
  int i = blockIdx.x * blockDim.x + threadIdx.x;
  const int stride = gridDim.x * blockDim.x;
  for (; i < TOT; i += stride) {
    int j = i;
    if (j < NX) {
      cast4(x, xb, j);
    } else if ((j -= NX) < NW1) {
      cast4(wq, wb, j);
    } else if ((j -= NW1) < NW2) {
      cast4(wk, wb + (size_t)NW1 * 4, j);
    } else if ((j -= NW2) < NW2) {
      cast4(wv, wb + (size_t)(NW1 + NW2) * 4, j);
    } else if ((j -= NW2) < NP) {
      cast4(wp, wpb, j);
    } else {
      j -= NP;  // rope table: entry (s, jj)
      const int s = j >> 5, jj = j & 31;
      const float inv = powf(10000.0f, -(float)jj * 0.03125f);
      const float ang = (float)s * inv;
      tab[j] = make_float2(cosf(ang), sinf(ang));
    }
  }
}

// ---------------- 2/4) B^T GEMM: 128^2, 3-buffer counted-vmcnt pipeline ------
// MODE 0: plain C store (proj).  MODE 1: q/k heads (bn 0..19) with fused
// RMSNorm + partial RoPE + q log2 prescale.  MODE 2: v heads (bn 20..23)
// with plain qkv store + pad-137 LDS transpose -> vt (pre-swizzled).
// MODE 1/2 are SEPARATE kernels so the v-transpose code doesn't inflate
// the q/k kernel's VGPR allocation (R16/R18: 84->104 VGPR cost ~12% occ).
template <typename CT, int MODE>
__global__ __launch_bounds__(256) void gemm_bt(const __bf16* __restrict__ A,
                                               const __bf16* __restrict__ B,
                                               CT* __restrict__ C, int N, int K, int nbn,
                                               const float2* __restrict__ tab,
                                               __bf16* __restrict__ vt) {
  __shared__ __align__(16) __bf16 SM[24576];  // 48 KB: 3xAs(4096) | 3xBs(4096)
  __bf16* Asb = SM;
  __bf16* Bsb = SM + 12288;
  const int nwg = gridDim.x;
  const int id = blockIdx.x;
  int bm, bn;
  if constexpr (MODE == 2) {
    bm = id >> 2;            // 0..31
    bn = 20 + (id & 3);      // v heads
  } else {
    const int xid = (id & 7) * (nwg >> 3) + (id >> 3);
    const int csz = nbn << 2;  // chunk = 4 bm x nbn (bn-inner-4)
    const int c = xid / csz;
    const int loc = xid - c * csz;
    bm = (c << 2) + (loc & 3);
    bn = loc >> 2;
  }
  const int t = threadIdx.x;
  const int l = t & 63, w = t >> 6;
  const int wr = w >> 1, wc = w & 1;
  const int lr = l & 15, lk = l >> 4;
  const __bf16* Ab = A + (size_t)bm * 128 * K;
  const __bf16* Bb = B + (size_t)bn * 128 * K;
  const int srow = t >> 2;                              // 0..63 (also +64)
  const int scol = ((t & 3) ^ ((srow >> 1) & 3)) << 3;  // inverse swizzle on src
  f32x4 acc[4][4] = {};

  auto stage = [&](int kt, int buf) {
    const int k0 = kt << 5;
    gload_lds16(Ab + (size_t)srow * K + k0 + scol, &Asb[buf * 4096 + t * 8]);
    gload_lds16(Ab + (size_t)(srow + 64) * K + k0 + scol, &Asb[buf * 4096 + 2048 + t * 8]);
    gload_lds16(Bb + (size_t)srow * K + k0 + scol, &Bsb[buf * 4096 + t * 8]);
    gload_lds16(Bb + (size_t)(srow + 64) * K + k0 + scol, &Bsb[buf * 4096 + 2048 + t * 8]);
  };

  stage(0, 0);
  stage(1, 1);
  asm volatile("s_waitcnt vmcnt(4)" ::: "memory");
  __builtin_amdgcn_s_barrier();

  const int NT = K >> 5;
  int cur = 0;
  for (int kt = 0; kt < NT; ++kt) {
    if (kt + 2 < NT) {
      int c2 = cur + 2;
      if (c2 >= 3) c2 -= 3;
      stage(kt + 2, c2);  // issue 2-ahead (async)
    }

    bf16x8 af[4], bfr[4];
#pragma unroll
    for (int m = 0; m < 4; ++m) {
      const int row = wr * 64 + m * 16 + lr;
      af[m] = *(const bf16x8*)&Asb[cur * 4096 + row * 32 + ((lk ^ ((row >> 1) & 3)) << 3)];
    }
#pragma unroll
    for (int n = 0; n < 4; ++n) {
      const int row = wc * 64 + n * 16 + lr;
      bfr[n] = *(const bf16x8*)&Bsb[cur * 4096 + row * 32 + ((lk ^ ((row >> 1) & 3)) << 3)];
    }
#pragma unroll
    for (int m = 0; m < 4; ++m)
#pragma unroll
      for (int n = 0; n < 4; ++n) acc[m][n] = MFMA16x16x32(af[m], bfr[n], acc[m][n]);

    if (kt + 2 < NT)
      asm volatile("s_waitcnt vmcnt(4)" ::: "memory");
    else
      asm volatile("s_waitcnt vmcnt(0)" ::: "memory");
    __builtin_amdgcn_s_barrier();

    ++cur;
    if (cur == 3) cur = 0;
  }

  if constexpr (MODE == 1) {
    // q/k heads: RMSNorm + partial RoPE (+ q log2-domain prescale)
    __syncthreads();  // drain all LDS traffic before SM reuse
    float* Ls = (float*)SM;  // [2][128] row sum-of-squares per col-wave
    float ssp[4][4];
#pragma unroll
    for (int m = 0; m < 4; ++m)
#pragma unroll
      for (int i = 0; i < 4; ++i) {
        float s = 0.0f;
#pragma unroll
        for (int n = 0; n < 4; ++n) s += acc[m][n][i] * acc[m][n][i];
#pragma unroll
        for (int off = 1; off < 16; off <<= 1) s += __shfl_xor(s, off);
        ssp[m][i] = s;
      }
    if (lr == 0) {
#pragma unroll
      for (int m = 0; m < 4; ++m)
#pragma unroll
        for (int i = 0; i < 4; ++i)
          Ls[wc * 128 + wr * 64 + m * 16 + lk * 4 + i] = ssp[m][i];
    }
    __syncthreads();
    const bool isq = (bn < 16);
    const float qs = isq ? 0.1275174457f : 1.0f;  // (1/sqrt(128))*log2(e)
#pragma unroll
    for (int m = 0; m < 4; ++m) {
#pragma unroll
      for (int i = 0; i < 4; ++i) {
        const int rl = wr * 64 + m * 16 + lk * 4 + i;
        const int rg = bm * 128 + rl;
        const float sc = rsqrtf((Ls[rl] + Ls[128 + rl]) * (1.0f / 128.0f) +
                                1.1920928955078125e-07f) *
                         qs;
        CT* Cr = C + (size_t)rg * N + bn * 128;
        if (wc == 0) {
          const int s = rg & 1023;
#pragma unroll
          for (int n = 0; n < 2; ++n) {
            const int j = n * 16 + lr;
            const float2 cs = tab[s * 32 + j];
            const float x1 = acc[m][n][i], x2 = acc[m][n + 2][i];
            Cr[j] = (CT)((x1 * cs.x + x2 * cs.y) * sc);
            Cr[j + 32] = (CT)((-x1 * cs.y + x2 * cs.x) * sc);
          }
        } else {
#pragma unroll
          for (int n = 0; n < 4; ++n)
            Cr[64 + n * 16 + lr] = (CT)(acc[m][n][i] * sc);
        }
      }
    }
    return;
  } else if constexpr (MODE == 2) {
    // v heads: plain qkv store + pad-137 LDS transpose -> vt (pre-swizzled)
#pragma unroll
    for (int m = 0; m < 4; ++m) {
      const int row0 = bm * 128 + wr * 64 + m * 16 + lk * 4;
#pragma unroll
      for (int n = 0; n < 4; ++n) {
        const int col = bn * 128 + wc * 64 + n * 16 + lr;
#pragma unroll
        for (int i = 0; i < 4; ++i)
          C[(size_t)(row0 + i) * N + col] = (CT)acc[m][n][i];
      }
    }
    __syncthreads();  // drain all LDS traffic before SM reuse
    __bf16* T = SM;   // [128][137] pad-137 transpose buffer (35072 B)
#pragma unroll
    for (int m = 0; m < 4; ++m) {
#pragma unroll
      for (int n = 0; n < 4; ++n) {
        const int cl = wc * 64 + n * 16 + lr;
#pragma unroll
        for (int i = 0; i < 4; ++i) {
          const int rl = wr * 64 + m * 16 + lk * 4 + i;
          T[rl * 137 + cl] = (__bf16)acc[m][n][i];
        }
      }
    }
    __syncthreads();
    const int bb = bm >> 3, s0g = (bm & 7) << 7;
    __bf16* dst = vt + (size_t)(bb * 4 + (bn - 20)) * 131072;
#pragma unroll
    for (int r = 0; r < 8; ++r) {
      const int off = r * 2048 + t * 8;
      const int dd = off >> 7, sc = off & 127;
      bf16x8 v;
#pragma unroll
      for (int j = 0; j < 8; ++j) v[j] = T[(sc + j) * 137 + dd];
      *(bf16x8*)&dst[(size_t)dd * 1024 + ((s0g + sc) ^ ((dd & 7) << 3))] = v;
    }
    return;
  } else {
#pragma unroll
    for (int m = 0; m < 4; ++m) {
      const int row0 = bm * 128 + wr * 64 + m * 16 + lk * 4;
#pragma unroll
      for (int n = 0; n < 4; ++n) {
        const int col = bn * 128 + wc * 64 + n * 16 + lr;
#pragma unroll
        for (int i = 0; i < 4; ++i) C[(size_t)(row0 + i) * N + col] = (CT)acc[m][n][i];
      }
    }
  }
}

// ---------------- 3) causal flash attention + v-projection correction ------
// KVBLK=128 SEQUENTIAL-PAIR + ones-MFMA row-sum denom + defer-max:
// 256 blocks (=1/CU) x 512 threads (8 waves); passes (7-pr, pr) => exactly
// 9 kv-iterations/block. Softmax denominator via MFMA(P, ones) row-sum.
// O/l rescale skipped unless running max grew by >8 (log2 domain).
__global__ __launch_bounds__(512) void attn_fwd(const __bf16* __restrict__ qkv,
                                                const __bf16* __restrict__ vt,
                                                __bf16* __restrict__ y) {
  const int id = blockIdx.x;
  const int g = (id & 7) | (((id >> 3) & 1) << 3);  // (b,kvh) group 0..15
  const int b = g >> 2, kvh = g & 3;
  const int hi = (id >> 4) & 3;
  const int pr = (id >> 6) & 3;
  const int h = kvh * 4 + hi;

  const int t = threadIdx.x;
  const int l = t & 63, w = t >> 6;  // 8 waves
  const int lr = l & 15, lk = l >> 4;
  const int lr8 = lr & 7;

  __shared__ __bf16 Ks[2][128 * 128];
  __shared__ __bf16 Vs[2][128 * 128];
  __shared__ __bf16 Ps[8][16 * 128];

  const size_t rb = (size_t)b * 1024;
  const __bf16* Kg0 = qkv + rb * 3072 + 2048 + kvh * 128;
  const __bf16* Vtb = vt + (size_t)(b * 4 + kvh) * 128 * 1024;

  const int srow = t >> 4;  // 0..31
  const int scg = t & 15;
  const int kcolg = (scg ^ (srow & 7)) << 3;  // inverse swizzle on K source

  auto stageK = [&](int kv0, int buf) {
#pragma unroll
    for (int r = 0; r < 4; ++r)
      gload_lds16(Kg0 + (size_t)(kv0 + r * 32 + srow) * 3072 + kcolg,
                  &Ks[buf][0] + r * 4096 + t * 8);
  };
  auto stageV = [&](int kv0, int buf) {
#pragma unroll
    for (int r = 0; r < 4; ++r)
      gload_lds16(Vtb + (size_t)(r * 32 + srow) * 1024 + kv0 + scg * 8,
                  &Vs[buf][0] + r * 4096 + t * 8);
  };

  bf16x8 onesb;
#pragma unroll
  for (int j = 0; j < 8; ++j) onesb[j] = (__bf16)1.0f;

#pragma unroll 1
  for (int pass = 0; pass < 2; ++pass) {
    const int qt = pass ? pr : (7 - pr);  // heavy pass first
    const int q0 = qt << 7;
    const int nt = qt + 1;

    bf16x8 aq[4];
    {
      const __bf16* qrow = qkv + (rb + q0 + w * 16 + lr) * 3072 + h * 128 + lk * 8;
#pragma unroll
      for (int kk = 0; kk < 4; ++kk) aq[kk] = *(const bf16x8*)(qrow + kk * 32);
    }

    float m_i[4], l_i[4];
    f32x4 o[8] = {};
#pragma unroll
    for (int i = 0; i < 4; ++i) {
      m_i[i] = -1e30f;
      l_i[i] = 0.0f;
    }

    const int rowg0 = q0 + w * 16 + lk * 4;

    stageK(0, 0);
    stageV(0, 0);
    __syncthreads();  // drains vmcnt -> buf0 ready

    for (int tt = 0; tt < nt; ++tt) {
      const int kv0 = tt << 7;
      const int cur = tt & 1;
      if (tt + 1 < nt) {
        stageK(kv0 + 128, cur ^ 1);
        stageV(kv0 + 128, cur ^ 1);
      }

      // S = Q K^T (log2-domain: q pre-scaled in gemm epilogue)
      f32x4 sacc[8] = {};
      __builtin_amdgcn_s_setprio(1);
#pragma unroll
      for (int kk = 0; kk < 4; ++kk) {
#pragma unroll
        for (int n = 0; n < 8; ++n) {
          const bf16x8 bk = *(const bf16x8*)&Ks[cur][(n * 16 + lr) * 128 +
                                                    ((kk * 32 + lk * 8) ^ (lr8 << 3))];
          sacc[n] = MFMA16x16x32(aq[kk], bk, sacc[n]);
        }
      }
      __builtin_amdgcn_s_setprio(0);

      // causal mask (diagonal tile only) + tile row-max
      float pm[4];
#pragma unroll
      for (int i = 0; i < 4; ++i) pm[i] = -1e30f;
      if (tt == qt) {
#pragma unroll
        for (int n = 0; n < 8; ++n) {
          const int colg = kv0 + n * 16 + lr;
#pragma unroll
          for (int i = 0; i < 4; ++i) {
            if (colg > rowg0 + i) sacc[n][i] = -1e30f;
            pm[i] = fmaxf(pm[i], sacc[n][i]);
          }
        }
      } else {
#pragma unroll
        for (int n = 0; n < 8; ++n)
#pragma unroll
          for (int i = 0; i < 4; ++i) pm[i] = fmaxf(pm[i], sacc[n][i]);
      }
#pragma unroll
      for (int i = 0; i < 4; ++i) {
        pm[i] = fmaxf(pm[i], __shfl_xor(pm[i], 1));
        pm[i] = fmaxf(pm[i], __shfl_xor(pm[i], 2));
        pm[i] = fmaxf(pm[i], __shfl_xor(pm[i], 4));
        pm[i] = fmaxf(pm[i], __shfl_xor(pm[i], 8));
      }

      // defer-max: rescale only when the running max grew by >8 (log2)
      const float dm = fmaxf(fmaxf(pm[0] - m_i[0], pm[1] - m_i[1]),
                             fmaxf(pm[2] - m_i[2], pm[3] - m_i[3]));
      if (__any(dm > 8.0f)) {
#pragma unroll
        for (int i = 0; i < 4; ++i) {
          const float mn = fmaxf(m_i[i], pm[i]);
          const float al = EXP2(m_i[i] - mn);
          m_i[i] = mn;
          l_i[i] *= al;
#pragma unroll
          for (int f = 0; f < 8; ++f) o[f][i] *= al;
        }
      }

      // P = exp2(S - m) -> Ps (bf16, swizzled)
#pragma unroll
      for (int n = 0; n < 8; ++n) {
#pragma unroll
        for (int i = 0; i < 4; ++i) {
          const float p = EXP2(sacc[n][i] - m_i[i]);
          const int prow = lk * 4 + i;
          Ps[w][prow * 128 + ((n * 16 + lr) ^ ((prow & 7) << 3))] = (__bf16)p;
        }
      }

      // O += P V ; l += P·1 (ones-MFMA row-sum, no shuffles)
      f32x4 lsum = {};
      __builtin_amdgcn_s_setprio(1);
#pragma unroll
      for (int ks = 0; ks < 4; ++ks) {
        const bf16x8 pa =
            *(const bf16x8*)&Ps[w][lr * 128 + ((ks * 32 + lk * 8) ^ (lr8 << 3))];
        lsum = MFMA16x16x32(pa, onesb, lsum);
#pragma unroll
        for (int f = 0; f < 8; ++f) {
          const bf16x8 vb = *(const bf16x8*)&Vs[cur][(f * 16 + lr) * 128 +
                                                     ((ks * 32 + lk * 8) ^ (lr8 << 3))];
          o[f] = MFMA16x16x32(pa, vb, o[f]);
        }
      }
      __builtin_amdgcn_s_setprio(0);
#pragma unroll
      for (int i = 0; i < 4; ++i) l_i[i] += lsum[i];

      __syncthreads();  // next tile staged (vmcnt drained) + all LDS reads done
    }

    // epilogue: normalize, v-projection correction, store bf16
#pragma unroll
    for (int i = 0; i < 4; ++i) {
      const int sg = rowg0 + i;
      const size_t mg = rb + sg;
      const __bf16* vp = qkv + mg * 3072 + 2560 + kvh * 128;
      const float invl = 1.0f / l_i[i];
      float vvv[8], yvv[8];
      float dyv = 0.0f, dvv = 0.0f;
#pragma unroll
      for (int f = 0; f < 8; ++f) {
        const float vf = (float)vp[f * 16 + lr];
        const float yf = o[f][i] * invl;
        vvv[f] = vf;
        yvv[f] = yf;
        dyv += yf * vf;
        dvv += vf * vf;
      }
#pragma unroll
      for (int off = 1; off < 16; off <<= 1) {
        dyv += __shfl_xor(dyv, off);
        dvv += __shfl_xor(dvv, off);
      }
      const float proj = dyv / fmaxf(dvv, 1e-6f);
      __bf16* yp = y + mg * 2048 + h * 128;
#pragma unroll
      for (int f = 0; f < 8; ++f) yp[f * 16 + lr] = (__bf16)(yvv[f] - proj * vvv[f]);
    }
  }
}

// ---------------------------------------------------------------------------
extern "C" void kernel_launch(void* const* d_in, const int* in_sizes, int n_in,
                              void* d_out, int out_size, void* d_ws, size_t ws_size,
                              hipStream_t stream) {
  const float* x = (const float*)d_in[0];
  const float* Wq = (const float*)d_in[2];
  const float* Wk = (const float*)d_in[3];
  const float* Wv = (const float*)d_in[4];
  const float* Wp = (const float*)d_in[5];
  float* out = (float*)d_out;

  __bf16* xb = (__bf16*)d_ws;                // 4096x2048
  __bf16* Wb = xb + (size_t)4096 * 2048;     // 3072x2048  [Wq;Wk;Wv]
  __bf16* Wpb = Wb + (size_t)3072 * 2048;    // 2048x2048
  __bf16* qkv = Wpb + (size_t)2048 * 2048;   // 4096x3072
  __bf16* yb = qkv + (size_t)4096 * 3072;    // 4096x2048
  float2* tab = (float2*)(yb + (size_t)4096 * 2048);  // 1024x32 cos/sin
  __bf16* vt = (__bf16*)(tab + 32768);       // 16x128x1024 transposed V

  prep<<<2048, 256, 0, stream>>>(x, Wq, Wk, Wv, Wp, xb, Wb, Wpb, tab);

  gemm_bt<__bf16, 1><<<640, 256, 0, stream>>>(xb, Wb, qkv, 3072, 2048, 20, tab, nullptr);
  gemm_bt<__bf16, 2><<<128, 256, 0, stream>>>(xb, Wb, qkv, 3072, 2048, 4, nullptr, vt);
  attn_fwd<<<256, 512, 0, stream>>>(qkv, vt, yb);
  gemm_bt<float, 0><<<512, 256, 0, stream>>>(yb, Wpb, out, 2048, 2048, 16, nullptr,
                                             nullptr);
}

// Round 20
// 172.466 us; speedup vs baseline: 1.1050x; 1.1050x over previous
//
#include <hip/hip_runtime.h>

// ---------------------------------------------------------------------------
// SelfAttention fused pipeline for MI355X (gfx950)
// B=4 S=1024 DIM=2048 H=16 KV=4 HD=128 ROPE_DIM=64
//
// Stages (all on `stream`), 4 launches  [best-measured config, R16 + pad137]:
//  1) prep: casts fp32->bf16 (x | Wq|Wk|Wv | Wproj) + rope cos/sin table
//  2) gemm_bt<FUSE>: qkv = xb @ Wcat^T (128^2, 3-buffer counted-vmcnt,
//     swizzled LDS) + fused RMSNorm/RoPE/log2-prescale (q,k) and fused
//     V-transpose -> vt via pad-137 LDS (v)
//  3) attn_fwd: causal flash attention + v-proj correction -> y bf16
//     (KVBLK=128 sequential-pair, ones-MFMA denom, defer-max)
//  4) gemm_bt: out = y @ Wproj^T (fp32 out)
// ---------------------------------------------------------------------------

typedef __attribute__((ext_vector_type(8))) __bf16 bf16x8;
typedef __attribute__((ext_vector_type(4))) __bf16 bf16x4;
typedef __attribute__((ext_vector_type(4))) float f32x4;

static_assert(sizeof(__bf16) == 2, "bf16 size");

#define MFMA16x16x32(a, b, c) __builtin_amdgcn_mfma_f32_16x16x32_bf16((a), (b), (c), 0, 0, 0)

#if __has_builtin(__builtin_amdgcn_exp2f)
#define EXP2(x) __builtin_amdgcn_exp2f(x)
#else
#define EXP2(x) exp2f(x)
#endif

__device__ __forceinline__ void gload_lds16(const void* g, void* l) {
  __builtin_amdgcn_global_load_lds((const __attribute__((address_space(1))) void*)g,
                                   (__attribute__((address_space(3))) void*)l, 16, 0, 0);
}

// ---------------- 1) prep: all casts + rope table, one kernel ----------------
__global__ __launch_bounds__(256) void prep(const float* __restrict__ x,
                                            const float* __restrict__ wq,
                                            const float* __restrict__ wk,
                                            const float* __restrict__ wv,
                                            const float* __restrict__ wp,
                                            __bf16* __restrict__ xb,
                                            __bf16* __restrict__ wb,
                                            __bf16* __restrict__ wpb,
                                            float2* __restrict__ tab) {
  constexpr int NX = 2097152;   // 4096*2048/4
  constexpr int NW1 = 1048576;  // 2048*2048/4
  constexpr int NW2 = 262144;   // 512*2048/4
  constexpr int NP = 1048576;   // 2048*2048/4
  constexpr int NT = 32768;     // 1024*32 rope table entries
  constexpr int TOT = NX + NW1 + 2 * NW2 + NP + NT;
  auto cast4 = [](const float* s, __bf16* d, int i) {
    f32x4 v = ((const f32x4*)s)[i];
    bf16x4 o;
    o[0] = (__bf16)v[0];
    o[1] = (__bf16)v[1];
    o[2] = (__bf16)v[2];
    o[3] = (__bf16)v[3];
    ((bf16x4*)d)[i] = o;
  };
  int i = blockIdx.x * blockDim.x + threadIdx.x;
  const int stride = gridDim.x * blockDim.x;
  for (; i < TOT; i += stride) {
    int j = i;
    if (j < NX) {
      cast4(x, xb, j);
    } else if ((j -= NX) < NW1) {
      cast4(wq, wb, j);
    } else if ((j -= NW1) < NW2) {
      cast4(wk, wb + (size_t)NW1 * 4, j);
    } else if ((j -= NW2) < NW2) {
      cast4(wv, wb + (size_t)(NW1 + NW2) * 4, j);
    } else if ((j -= NW2) < NP) {
      cast4(wp, wpb, j);
    } else {
      j -= NP;  // rope table: entry (s, jj)
      const int s = j >> 5, jj = j & 31;
      const float inv = powf(10000.0f, -(float)jj * 0.03125f);
      const float ang = (float)s * inv;
      tab[j] = make_float2(cosf(ang), sinf(ang));
    }
  }
}

// ---------------- 2/4) B^T GEMM: 128^2, 3-buffer counted-vmcnt pipeline ------
// FUSE epilogue: bn 0-19 (q,k heads) -> RMSNorm + RoPE + q log2 prescale;
// bn 20-23 (v heads) -> plain qkv store + pad-137 LDS transpose -> vt
// (pad 137: elem-step 8*137 -> bank-step 4 mod 32 -> 2-way aliasing = free).
template <typename CT, bool FUSE>
__global__ __launch_bounds__(256) void gemm_bt(const __bf16* __restrict__ A,
                                               const __bf16* __restrict__ B,
                                               CT* __restrict__ C, int N, int K, int nbn,
                                               const float2* __restrict__ tab,
                                               __bf16* __restrict__ vt) {
  __shared__ __align__(16) __bf16 SM[24576];  // 48 KB: 3xAs(4096) | 3xBs(4096)
  __bf16* Asb = SM;
  __bf16* Bsb = SM + 12288;
  const int nwg = gridDim.x;
  const int id = blockIdx.x;
  const int xid = (id & 7) * (nwg >> 3) + (id >> 3);
  const int bm = xid / nbn;
  const int bn = xid - bm * nbn;
  const int t = threadIdx.x;
  const int l = t & 63, w = t >> 6;
  const int wr = w >> 1, wc = w & 1;
  const int lr = l & 15, lk = l >> 4;
  const __bf16* Ab = A + (size_t)bm * 128 * K;
  const __bf16* Bb = B + (size_t)bn * 128 * K;
  const int srow = t >> 2;                              // 0..63 (also +64)
  const int scol = ((t & 3) ^ ((srow >> 1) & 3)) << 3;  // inverse swizzle on src
  f32x4 acc[4][4] = {};

  auto stage = [&](int kt, int buf) {
    const int k0 = kt << 5;
    gload_lds16(Ab + (size_t)srow * K + k0 + scol, &Asb[buf * 4096 + t * 8]);
    gload_lds16(Ab + (size_t)(srow + 64) * K + k0 + scol, &Asb[buf * 4096 + 2048 + t * 8]);
    gload_lds16(Bb + (size_t)srow * K + k0 + scol, &Bsb[buf * 4096 + t * 8]);
    gload_lds16(Bb + (size_t)(srow + 64) * K + k0 + scol, &Bsb[buf * 4096 + 2048 + t * 8]);
  };

  stage(0, 0);
  stage(1, 1);
  asm volatile("s_waitcnt vmcnt(4)" ::: "memory");
  __builtin_amdgcn_s_barrier();

  const int NT = K >> 5;
  int cur = 0;
  for (int kt = 0; kt < NT; ++kt) {
    if (kt + 2 < NT) {
      int c2 = cur + 2;
      if (c2 >= 3) c2 -= 3;
      stage(kt + 2, c2);  // issue 2-ahead (async)
    }

    bf16x8 af[4], bfr[4];
#pragma unroll
    for (int m = 0; m < 4; ++m) {
      const int row = wr * 64 + m * 16 + lr;
      af[m] = *(const bf16x8*)&Asb[cur * 4096 + row * 32 + ((lk ^ ((row >> 1) & 3)) << 3)];
    }
#pragma unroll
    for (int n = 0; n < 4; ++n) {
      const int row = wc * 64 + n * 16 + lr;
      bfr[n] = *(const bf16x8*)&Bsb[cur * 4096 + row * 32 + ((lk ^ ((row >> 1) & 3)) << 3)];
    }
#pragma unroll
    for (int m = 0; m < 4; ++m)
#pragma unroll
      for (int n = 0; n < 4; ++n) acc[m][n] = MFMA16x16x32(af[m], bfr[n], acc[m][n]);

    if (kt + 2 < NT)
      asm volatile("s_waitcnt vmcnt(4)" ::: "memory");
    else
      asm volatile("s_waitcnt vmcnt(0)" ::: "memory");
    __builtin_amdgcn_s_barrier();

    ++cur;
    if (cur == 3) cur = 0;
  }

  if constexpr (FUSE) {
    if (bn < 20) {
      // q/k heads: RMSNorm + partial RoPE (+ q log2-domain prescale)
      __syncthreads();  // drain all LDS traffic before SM reuse
      float* Ls = (float*)SM;  // [2][128] row sum-of-squares per col-wave
      float ssp[4][4];
#pragma unroll
      for (int m = 0; m < 4; ++m)
#pragma unroll
        for (int i = 0; i < 4; ++i) {
          float s = 0.0f;
#pragma unroll
          for (int n = 0; n < 4; ++n) s += acc[m][n][i] * acc[m][n][i];
#pragma unroll
          for (int off = 1; off < 16; off <<= 1) s += __shfl_xor(s, off);
          ssp[m][i] = s;
        }
      if (lr == 0) {
#pragma unroll
        for (int m = 0; m < 4; ++m)
#pragma unroll
          for (int i = 0; i < 4; ++i)
            Ls[wc * 128 + wr * 64 + m * 16 + lk * 4 + i] = ssp[m][i];
      }
      __syncthreads();
      const bool isq = (bn < 16);
      const float qs = isq ? 0.1275174457f : 1.0f;  // (1/sqrt(128))*log2(e)
#pragma unroll
      for (int m = 0; m < 4; ++m) {
#pragma unroll
        for (int i = 0; i < 4; ++i) {
          const int rl = wr * 64 + m * 16 + lk * 4 + i;
          const int rg = bm * 128 + rl;
          const float sc =
              rsqrtf((Ls[rl] + Ls[128 + rl]) * (1.0f / 128.0f) +
                     1.1920928955078125e-07f) *
              qs;
          CT* Cr = C + (size_t)rg * N + bn * 128;
          if (wc == 0) {
            const int s = rg & 1023;
#pragma unroll
            for (int n = 0; n < 2; ++n) {
              const int j = n * 16 + lr;
              const float2 cs = tab[s * 32 + j];
              const float x1 = acc[m][n][i], x2 = acc[m][n + 2][i];
              Cr[j] = (CT)((x1 * cs.x + x2 * cs.y) * sc);
              Cr[j + 32] = (CT)((-x1 * cs.y + x2 * cs.x) * sc);
            }
          } else {
#pragma unroll
            for (int n = 0; n < 4; ++n)
              Cr[64 + n * 16 + lr] = (CT)(acc[m][n][i] * sc);
          }
        }
      }
      return;
    } else {
      // v heads: plain qkv store + pad-137 LDS transpose -> vt (pre-swizzled)
#pragma unroll
      for (int m = 0; m < 4; ++m) {
        const int row0 = bm * 128 + wr * 64 + m * 16 + lk * 4;
#pragma unroll
        for (int n = 0; n < 4; ++n) {
          const int col = bn * 128 + wc * 64 + n * 16 + lr;
#pragma unroll
          for (int i = 0; i < 4; ++i)
            C[(size_t)(row0 + i) * N + col] = (CT)acc[m][n][i];
        }
      }
      __syncthreads();  // drain all LDS traffic before SM reuse
      __bf16* T = SM;   // [128][137] pad-137 transpose buffer (35072 B)
#pragma unroll
      for (int m = 0; m < 4; ++m) {
#pragma unroll
        for (int n = 0; n < 4; ++n) {
          const int cl = wc * 64 + n * 16 + lr;
#pragma unroll
          for (int i = 0; i < 4; ++i) {
            const int rl = wr * 64 + m * 16 + lk * 4 + i;
            T[rl * 137 + cl] = (__bf16)acc[m][n][i];
          }
        }
      }
      __syncthreads();
      const int bb = bm >> 3, s0g = (bm & 7) << 7;
      __bf16* dst = vt + (size_t)(bb * 4 + (bn - 20)) * 131072;
#pragma unroll
      for (int r = 0; r < 8; ++r) {
        const int off = r * 2048 + t * 8;
        const int dd = off >> 7, sc = off & 127;
        bf16x8 v;
#pragma unroll
        for (int j = 0; j < 8; ++j) v[j] = T[(sc + j) * 137 + dd];
        *(bf16x8*)&dst[(size_t)dd * 1024 + ((s0g + sc) ^ ((dd & 7) << 3))] = v;
      }
      return;
    }
  }

#pragma unroll
  for (int m = 0; m < 4; ++m) {
    const int row0 = bm * 128 + wr * 64 + m * 16 + lk * 4;
#pragma unroll
    for (int n = 0; n < 4; ++n) {
      const int col = bn * 128 + wc * 64 + n * 16 + lr;
#pragma unroll
      for (int i = 0; i < 4; ++i) C[(size_t)(row0 + i) * N + col] = (CT)acc[m][n][i];
    }
  }
}

// ---------------- 3) causal flash attention + v-projection correction ------
// KVBLK=128 SEQUENTIAL-PAIR + ones-MFMA row-sum denom + defer-max:
// 256 blocks (=1/CU) x 512 threads (8 waves); passes (7-pr, pr) => exactly
// 9 kv-iterations/block. Softmax denominator via MFMA(P, ones) row-sum.
// O/l rescale skipped unless running max grew by >8 (log2 domain).
__global__ __launch_bounds__(512) void attn_fwd(const __bf16* __restrict__ qkv,
                                                const __bf16* __restrict__ vt,
                                                __bf16* __restrict__ y) {
  const int id = blockIdx.x;
  const int g = (id & 7) | (((id >> 3) & 1) << 3);  // (b,kvh) group 0..15
  const int b = g >> 2, kvh = g & 3;
  const int hi = (id >> 4) & 3;
  const int pr = (id >> 6) & 3;
  const int h = kvh * 4 + hi;

  const int t = threadIdx.x;
  const int l = t & 63, w = t >> 6;  // 8 waves
  const int lr = l & 15, lk = l >> 4;
  const int lr8 = lr & 7;

  __shared__ __bf16 Ks[2][128 * 128];
  __shared__ __bf16 Vs[2][128 * 128];
  __shared__ __bf16 Ps[8][16 * 128];

  const size_t rb = (size_t)b * 1024;
  const __bf16* Kg0 = qkv + rb * 3072 + 2048 + kvh * 128;
  const __bf16* Vtb = vt + (size_t)(b * 4 + kvh) * 128 * 1024;

  const int srow = t >> 4;  // 0..31
  const int scg = t & 15;
  const int kcolg = (scg ^ (srow & 7)) << 3;  // inverse swizzle on K source

  auto stageK = [&](int kv0, int buf) {
#pragma unroll
    for (int r = 0; r < 4; ++r)
      gload_lds16(Kg0 + (size_t)(kv0 + r * 32 + srow) * 3072 + kcolg,
                  &Ks[buf][0] + r * 4096 + t * 8);
  };
  auto stageV = [&](int kv0, int buf) {
#pragma unroll
    for (int r = 0; r < 4; ++r)
      gload_lds16(Vtb + (size_t)(r * 32 + srow) * 1024 + kv0 + scg * 8,
                  &Vs[buf][0] + r * 4096 + t * 8);
  };

  bf16x8 onesb;
#pragma unroll
  for (int j = 0; j < 8; ++j) onesb[j] = (__bf16)1.0f;

#pragma unroll 1
  for (int pass = 0; pass < 2; ++pass) {
    const int qt = pass ? pr : (7 - pr);  // heavy pass first
    const int q0 = qt << 7;
    const int nt = qt + 1;

    bf16x8 aq[4];
    {
      const __bf16* qrow = qkv + (rb + q0 + w * 16 + lr) * 3072 + h * 128 + lk * 8;
#pragma unroll
      for (int kk = 0; kk < 4; ++kk) aq[kk] = *(const bf16x8*)(qrow + kk * 32);
    }

    float m_i[4], l_i[4];
    f32x4 o[8] = {};
#pragma unroll
    for (int i = 0; i < 4; ++i) {
      m_i[i] = -1e30f;
      l_i[i] = 0.0f;
    }

    const int rowg0 = q0 + w * 16 + lk * 4;

    stageK(0, 0);
    stageV(0, 0);
    __syncthreads();  // drains vmcnt -> buf0 ready

    for (int tt = 0; tt < nt; ++tt) {
      const int kv0 = tt << 7;
      const int cur = tt & 1;
      if (tt + 1 < nt) {
        stageK(kv0 + 128, cur ^ 1);
        stageV(kv0 + 128, cur ^ 1);
      }

      // S = Q K^T (log2-domain: q pre-scaled in gemm epilogue)
      f32x4 sacc[8] = {};
      __builtin_amdgcn_s_setprio(1);
#pragma unroll
      for (int kk = 0; kk < 4; ++kk) {
#pragma unroll
        for (int n = 0; n < 8; ++n) {
          const bf16x8 bk = *(const bf16x8*)&Ks[cur][(n * 16 + lr) * 128 +
                                                    ((kk * 32 + lk * 8) ^ (lr8 << 3))];
          sacc[n] = MFMA16x16x32(aq[kk], bk, sacc[n]);
        }
      }
      __builtin_amdgcn_s_setprio(0);

      // causal mask (diagonal tile only) + tile row-max
      float pm[4];
#pragma unroll
      for (int i = 0; i < 4; ++i) pm[i] = -1e30f;
      if (tt == qt) {
#pragma unroll
        for (int n = 0; n < 8; ++n) {
          const int colg = kv0 + n * 16 + lr;
#pragma unroll
          for (int i = 0; i < 4; ++i) {
            if (colg > rowg0 + i) sacc[n][i] = -1e30f;
            pm[i] = fmaxf(pm[i], sacc[n][i]);
          }
        }
      } else {
#pragma unroll
        for (int n = 0; n < 8; ++n)
#pragma unroll
          for (int i = 0; i < 4; ++i) pm[i] = fmaxf(pm[i], sacc[n][i]);
      }
#pragma unroll
      for (int i = 0; i < 4; ++i) {
        pm[i] = fmaxf(pm[i], __shfl_xor(pm[i], 1));
        pm[i] = fmaxf(pm[i], __shfl_xor(pm[i], 2));
        pm[i] = fmaxf(pm[i], __shfl_xor(pm[i], 4));
        pm[i] = fmaxf(pm[i], __shfl_xor(pm[i], 8));
      }

      // defer-max: rescale only when the running max grew by >8 (log2)
      const float dm = fmaxf(fmaxf(pm[0] - m_i[0], pm[1] - m_i[1]),
                             fmaxf(pm[2] - m_i[2], pm[3] - m_i[3]));
      if (__any(dm > 8.0f)) {
#pragma unroll
        for (int i = 0; i < 4; ++i) {
          const float mn = fmaxf(m_i[i], pm[i]);
          const float al = EXP2(m_i[i] - mn);
          m_i[i] = mn;
          l_i[i] *= al;
#pragma unroll
          for (int f = 0; f < 8; ++f) o[f][i] *= al;
        }
      }

      // P = exp2(S - m) -> Ps (bf16, swizzled)
#pragma unroll
      for (int n = 0; n < 8; ++n) {
#pragma unroll
        for (int i = 0; i < 4; ++i) {
          const float p = EXP2(sacc[n][i] - m_i[i]);
          const int prow = lk * 4 + i;
          Ps[w][prow * 128 + ((n * 16 + lr) ^ ((prow & 7) << 3))] = (__bf16)p;
        }
      }

      // O += P V ; l += P·1 (ones-MFMA row-sum, no shuffles)
      f32x4 lsum = {};
      __builtin_amdgcn_s_setprio(1);
#pragma unroll
      for (int ks = 0; ks < 4; ++ks) {
        const bf16x8 pa =
            *(const bf16x8*)&Ps[w][lr * 128 + ((ks * 32 + lk * 8) ^ (lr8 << 3))];
        lsum = MFMA16x16x32(pa, onesb, lsum);
#pragma unroll
        for (int f = 0; f < 8; ++f) {
          const bf16x8 vb = *(const bf16x8*)&Vs[cur][(f * 16 + lr) * 128 +
                                                     ((ks * 32 + lk * 8) ^ (lr8 << 3))];
          o[f] = MFMA16x16x32(pa, vb, o[f]);
        }
      }
      __builtin_amdgcn_s_setprio(0);
#pragma unroll
      for (int i = 0; i < 4; ++i) l_i[i] += lsum[i];

      __syncthreads();  // next tile staged (vmcnt drained) + all LDS reads done
    }

    // epilogue: normalize, v-projection correction, store bf16
#pragma unroll
    for (int i = 0; i < 4; ++i) {
      const int sg = rowg0 + i;
      const size_t mg = rb + sg;
      const __bf16* vp = qkv + mg * 3072 + 2560 + kvh * 128;
      const float invl = 1.0f / l_i[i];
      float vvv[8], yvv[8];
      float dyv = 0.0f, dvv = 0.0f;
#pragma unroll
      for (int f = 0; f < 8; ++f) {
        const float vf = (float)vp[f * 16 + lr];
        const float yf = o[f][i] * invl;
        vvv[f] = vf;
        yvv[f] = yf;
        dyv += yf * vf;
        dvv += vf * vf;
      }
#pragma unroll
      for (int off = 1; off < 16; off <<= 1) {
        dyv += __shfl_xor(dyv, off);
        dvv += __shfl_xor(dvv, off);
      }
      const float proj = dyv / fmaxf(dvv, 1e-6f);
      __bf16* yp = y + mg * 2048 + h * 128;
#pragma unroll
      for (int f = 0; f < 8; ++f) yp[f * 16 + lr] = (__bf16)(yvv[f] - proj * vvv[f]);
    }
  }
}

// ---------------------------------------------------------------------------
extern "C" void kernel_launch(void* const* d_in, const int* in_sizes, int n_in,
                              void* d_out, int out_size, void* d_ws, size_t ws_size,
                              hipStream_t stream) {
  const float* x = (const float*)d_in[0];
  const float* Wq = (const float*)d_in[2];
  const float* Wk = (const float*)d_in[3];
  const float* Wv = (const float*)d_in[4];
  const float* Wp = (const float*)d_in[5];
  float* out = (float*)d_out;

  __bf16* xb = (__bf16*)d_ws;                // 4096x2048
  __bf16* Wb = xb + (size_t)4096 * 2048;     // 3072x2048  [Wq;Wk;Wv]
  __bf16* Wpb = Wb + (size_t)3072 * 2048;    // 2048x2048
  __bf16* qkv = Wpb + (size_t)2048 * 2048;   // 4096x3072
  __bf16* yb = qkv + (size_t)4096 * 3072;    // 4096x2048
  float2* tab = (float2*)(yb + (size_t)4096 * 2048);  // 1024x32 cos/sin
  __bf16* vt = (__bf16*)(tab + 32768);       // 16x128x1024 transposed V

  prep<<<2048, 256, 0, stream>>>(x, Wq, Wk, Wv, Wp, xb, Wb, Wpb, tab);

  gemm_bt<__bf16, true><<<768, 256, 0, stream>>>(xb, Wb, qkv, 3072, 2048, 24, tab, vt);
  attn_fwd<<<256, 512, 0, stream>>>(qkv, vt, yb);
  gemm_bt<float, false><<<512, 256, 0, stream>>>(yb, Wpb, out, 2048, 2048, 16, nullptr,
                                                 nullptr);
}